// Round 5
// baseline (1485.702 us; speedup 1.0000x reference)
//
#include <hip/hip_runtime.h>
#include <math.h>

// Problem constants: T=1024, B=8, H=8, N=32. D = H*N*N = 8192.
#define T_STEPS 1024
#define NBH     64
#define NTILE   65536
#define NJOBS   4096            // 64 bh * 64 chunks of 16 t
#define MAGIC   0x13579BDFu
#define NCONS   128             // consumer blocks (512 scan waves)
#define NPROD   384             // producer blocks (1536 stats waves)
#define PWAVES  (NPROD * 4)

static __device__ __forceinline__ float fast_rcp(float x) {
  return __builtin_amdgcn_rcpf(x);
}
static __device__ __forceinline__ float fast_sigmoid(float x) {
  return fast_rcp(1.0f + __expf(-x));
}
// tanh(x) where y = 2x is passed: tanh = 1 - 2/(1+e^{2x})
static __device__ __forceinline__ float fast_tanh2(float y) {
  return 1.0f - 2.0f * fast_rcp(1.0f + __expf(y));
}

template <int CTRL>
static __device__ __forceinline__ float dpp_add(float x) {
  int y = __builtin_amdgcn_update_dpp(0, __float_as_int(x), CTRL, 0xF, 0xF, true);
  return x + __int_as_float(y);
}

// Butterfly sum over each 16-lane group; result in all 16 lanes. Pure DPP.
static __device__ __forceinline__ float red16(float x) {
  x = dpp_add<0xB1>(x);    // quad_perm xor 1
  x = dpp_add<0x4E>(x);    // quad_perm xor 2
  x = dpp_add<0x141>(x);   // row_half_mirror
  x = dpp_add<0x140>(x);   // row_mirror
  return x;
}

// ---------------------------------------------------------------------------
// Fused producer/consumer kernel.
//  blocks [0, NCONS)         : consumers — the serial scan (verified R4 code,
//                              8-step sub-block double buffer).
//  blocks [NCONS, NCONS+NPROD): producers — per-tile stats (verified R4 code),
//                              jobs in chunk-major order, flag per job.
// Stats layout (t-major): knT2[bh][elem][t], vvT2[bh][elem][t] (=2v),
// bbT2[bh][t] (=2*beta). flags[chunk*64 + bh].
// ---------------------------------------------------------------------------
__global__ __launch_bounds__(256, 4) void fused_kernel(
    const float* __restrict__ x, const float* __restrict__ S0,
    const float* __restrict__ scale_p, const float* __restrict__ bias_p,
    float* __restrict__ knT2, float* __restrict__ vvT2,
    float* __restrict__ bbT2, unsigned int* __restrict__ flags,
    float* __restrict__ out, float* __restrict__ Sfin) {
  const int tid = threadIdx.x;
  const int wib = tid >> 6;
  const int l   = tid & 63;

  __shared__ float kn_s[4][512];
  __shared__ float vv_s[4][512];
  __shared__ float bb_s[4][16];

  if (blockIdx.x >= NCONS) {
    // ------------------------------ producer ------------------------------
    const int m = l & 7;
    const int g = l >> 3;
    const float sc = scale_p[0], bi = bias_p[0];
    float* ks = kn_s[wib];
    float* vs = vv_s[wib];
    float* bs = bb_s[wib];
    const int pw = (blockIdx.x - NCONS) * 4 + wib;

    for (int job = pw; job < NJOBS; job += PWAVES) {
      const int bh = job & 63;          // chunk-major: early t first
      const int t0 = (job >> 6) << 4;

      const float4* xp = (const float4*)(x + ((size_t)t0 * 64 + bh) * 1024);
      float4 a0 = xp[l], a1 = xp[l + 64], a2 = xp[l + 128], a3 = xp[l + 192];

      for (int tt = 0; tt < 16; ++tt) {
        float4 b0, b1, b2, b3;
        if (tt < 15) {
          const float4* xn = xp + (size_t)(tt + 1) * 16384;
          b0 = xn[l]; b1 = xn[l + 64]; b2 = xn[l + 128]; b3 = xn[l + 192];
        }

        float r0 = (a0.x + a0.y) + (a0.z + a0.w);
        float r1 = (a1.x + a1.y) + (a1.z + a1.w);
        float r2 = (a2.x + a2.y) + (a2.z + a2.w);
        float r3 = (a3.x + a3.y) + (a3.z + a3.w);
        r0 += __shfl_xor(r0, 1); r1 += __shfl_xor(r1, 1);
        r2 += __shfl_xor(r2, 1); r3 += __shfl_xor(r3, 1);
        r0 += __shfl_xor(r0, 2); r1 += __shfl_xor(r1, 2);
        r2 += __shfl_xor(r2, 2); r3 += __shfl_xor(r3, 2);
        r0 += __shfl_xor(r0, 4); r1 += __shfl_xor(r1, 4);
        r2 += __shfl_xor(r2, 4); r3 += __shfl_xor(r3, 4);

        float c0 = a0.x + a1.x + a2.x + a3.x;
        float c1 = a0.y + a1.y + a2.y + a3.y;
        float c2 = a0.z + a1.z + a2.z + a3.z;
        float c3 = a0.w + a1.w + a2.w + a3.w;
        c0 += __shfl_xor(c0, 8);  c1 += __shfl_xor(c1, 8);
        c2 += __shfl_xor(c2, 8);  c3 += __shfl_xor(c3, 8);
        c0 += __shfl_xor(c0, 16); c1 += __shfl_xor(c1, 16);
        c2 += __shfl_xor(c2, 16); c3 += __shfl_xor(c3, 16);
        c0 += __shfl_xor(c0, 32); c1 += __shfl_xor(c1, 32);
        c2 += __shfl_xor(c2, 32); c3 += __shfl_xor(c3, 32);

        float t1 = (r0 + r1) + (r2 + r3);
        float t2 = (r0 * r0 + r1 * r1) + (r2 * r2 + r3 * r3);
        t1 += __shfl_xor(t1, 8);  t2 += __shfl_xor(t2, 8);
        t1 += __shfl_xor(t1, 16); t2 += __shfl_xor(t2, 16);
        t1 += __shfl_xor(t1, 32); t2 += __shfl_xor(t2, 32);
        const float norm = sqrtf(t2) * (1.0f / 32.0f);
        const float kscl = (1.0f / 32.0f) * fast_rcp(norm + 1e-6f);

        if (m == 0) {
          ks[(g)      * 16 + tt] = r0 * kscl;
          ks[(g + 8)  * 16 + tt] = r1 * kscl;
          ks[(g + 16) * 16 + tt] = r2 * kscl;
          ks[(g + 24) * 16 + tt] = r3 * kscl;
        }
        if (l < 8) {      // V2 = 2*colmean = colsum/16
          vs[(4 * m)     * 16 + tt] = c0 * (1.0f / 16.0f);
          vs[(4 * m + 1) * 16 + tt] = c1 * (1.0f / 16.0f);
          vs[(4 * m + 2) * 16 + tt] = c2 * (1.0f / 16.0f);
          vs[(4 * m + 3) * 16 + tt] = c3 * (1.0f / 16.0f);
        }
        if (l == 0) {     // B2 = 2*beta
          const float mean = t1 * (1.0f / 1024.0f);
          bs[tt] = 2.0f * fast_sigmoid(sc * mean + bi);
        }

        a0 = b0; a1 = b1; a2 = b2; a3 = b3;
      }

      const size_t rowbase = (size_t)bh * 32 * T_STEPS + t0;
#pragma unroll
      for (int rep = 0; rep < 2; ++rep) {
        const int c = l + rep * 64;
        const int e = c >> 2;
        const int q = c & 3;
        const float4 kv = *(const float4*)&ks[e * 16 + q * 4];
        const float4 vq = *(const float4*)&vs[e * 16 + q * 4];
        *(float4*)(knT2 + rowbase + (size_t)e * T_STEPS + q * 4) = kv;
        *(float4*)(vvT2 + rowbase + (size_t)e * T_STEPS + q * 4) = vq;
      }
      if (l < 4) {
        const float4 bv = *(const float4*)&bs[l * 4];
        *(float4*)(bbT2 + (size_t)bh * T_STEPS + t0 + l * 4) = bv;
      }

      __threadfence();                           // device-scope release
      if (l == 0) atomicExch(&flags[job], MAGIC);
    }
  } else {
    // ------------------------------ consumer ------------------------------
    const int g = l >> 4;                        // group in wave (0..3)
    const int s = l & 15;
    const int w = blockIdx.x * 4 + wib;          // 0..511
    const int bh = w >> 3;
    const int i  = (w & 7) * 4 + g;
    const int chain = bh * 32 + i;

    const float2 sini =
        *(const float2*)(S0 + (size_t)bh * 1024 + i * 32 + 2 * s);
    float Sa = sini.x, Sb = sini.y;

    const float* kn0p = knT2 + ((size_t)bh * 32 + 2 * s) * T_STEPS;
    const float* kn1p = kn0p + T_STEPS;
    const float* vp   = vvT2 + ((size_t)bh * 32 + i) * T_STEPS;
    const float* bp   = bbT2 + (size_t)bh * T_STEPS;
    float* outp = out + chain;

    float ak0[8], ak1[8], av[8], ab[8];          // even sub-block
    float bk0[8], bk1[8], bv[8], bbuf[8];        // odd sub-block

#define WAITC(c)                                                          \
  do {                                                                    \
    if (l == 0) {                                                         \
      while (atomicOr(&flags[(size_t)(c)*64 + bh], 0u) != MAGIC)          \
        __builtin_amdgcn_s_sleep(16);                                     \
    }                                                                     \
    __threadfence();  /* device-scope acquire */                          \
  } while (0)

#define LOADSB(K0, K1, VV, BE, sb)                                        \
  do {                                                                    \
    const int _t = (sb)*8;                                                \
    *(float4*)&K0[0] = *(const float4*)(kn0p + _t);                       \
    *(float4*)&K0[4] = *(const float4*)(kn0p + _t + 4);                   \
    *(float4*)&K1[0] = *(const float4*)(kn1p + _t);                       \
    *(float4*)&K1[4] = *(const float4*)(kn1p + _t + 4);                   \
    *(float4*)&VV[0] = *(const float4*)(vp + _t);                         \
    *(float4*)&VV[4] = *(const float4*)(vp + _t + 4);                     \
    *(float4*)&BE[0] = *(const float4*)(bp + _t);                         \
    *(float4*)&BE[4] = *(const float4*)(bp + _t + 4);                     \
  } while (0)

#define COMPUTE8(K0, K1, VV, BE, OFF)                                     \
  do {                                                                    \
    _Pragma("unroll")                                                     \
    for (int u = 0; u < 8; ++u) {                                         \
      const float c0 = K0[u], c1 = K1[u];                                 \
      const float r  = red16(Sa * c0 + Sb * c1);                          \
      const float D2 = fmaf(-2.0f, r, VV[u]);                             \
      const float B2 = BE[u];                                             \
      Sa = fast_tanh2(fmaf(B2, Sa, D2 * c0));                             \
      Sb = fast_tanh2(fmaf(B2, Sb, D2 * c1));                             \
      const float qv = red16(Sa * c0 + Sb * c1);                          \
      const float o  = qv * qv * fast_sigmoid(qv);                        \
      oacc = ((u + (OFF)) == s) ? o : oacc;                               \
    }                                                                     \
  } while (0)

    WAITC(0);
    LOADSB(ak0, ak1, av, ab, 0);
    LOADSB(bk0, bk1, bv, bbuf, 1);
    float oacc = 0.0f;

    for (int c = 0; c < 64; ++c) {               // window of 16 t
      COMPUTE8(ak0, ak1, av, ab, 0);             // sub-block 2c
      if (c < 63) {
        WAITC(c + 1);                            // covers sb 2c+2, 2c+3
        LOADSB(ak0, ak1, av, ab, 2 * c + 2);     // hidden behind next compute
      }
      COMPUTE8(bk0, bk1, bv, bbuf, 8);           // sub-block 2c+1
      outp[(size_t)(c * 16 + s) * 2048] = oacc;
      if (c < 63) LOADSB(bk0, bk1, bv, bbuf, 2 * c + 3);
    }

#undef WAITC
#undef LOADSB
#undef COMPUTE8

    float2 sfin; sfin.x = Sa; sfin.y = Sb;
    *(float2*)(Sfin + (size_t)bh * 1024 + i * 32 + 2 * s) = sfin;
  }
}

extern "C" void kernel_launch(void* const* d_in, const int* in_sizes, int n_in,
                              void* d_out, int out_size, void* d_ws, size_t ws_size,
                              hipStream_t stream) {
  const float* x     = (const float*)d_in[0];   // [1024, 8, 8192] f32
  const float* S0    = (const float*)d_in[1];   // [8, 8, 32, 32] f32
  const float* scale = (const float*)d_in[2];   // scalar
  const float* bias  = (const float*)d_in[3];   // scalar
  float* out = (float*)d_out;                   // [1024,8,256] then S_final

  float* knT2 = (float*)d_ws;                   // [64][32][1024]
  float* vvT2 = knT2 + (size_t)NTILE * 32;      // [64][32][1024]  (2*v)
  float* bbT2 = vvT2 + (size_t)NTILE * 32;      // [64][1024]      (2*beta)
  unsigned int* flags = (unsigned int*)(bbT2 + (size_t)NBH * T_STEPS);
  // total ws use: ~16.3 MB + 16 KB flags

  hipMemsetAsync(flags, 0, NJOBS * sizeof(unsigned int), stream);

  float* Sfin = out + (size_t)T_STEPS * 2048;
  fused_kernel<<<NCONS + NPROD, 256, 0, stream>>>(
      x, S0, scale, bias, knT2, vvT2, bbT2, flags, out, Sfin);
}